// Round 4
// baseline (204.106 us; speedup 1.0000x reference)
//
#include <hip/hip_runtime.h>

#define BATCH 262144
#define NI 9
#define NH 100
#define NO 2
#define T 25

// One thread per batch element. Entire hot path is one fixed-register asm
// block so the RA cannot park the 50 per-timestep accumulators in AGPRs
// (R1-R3: compiler kept them in AGPRs -> 10.5 VALU/(h,t) instead of 6).
//
// Register map (all clobbered):
//   v10 c      v11 mem    v12 spk    v13 pk-hi dummy  v14 store voffset (b*8)
//   v[16+2t : 17+2t] t=0..24 : packed acc pair (acc0[t], acc1[t])
//   v66,v67 phase-2 c0,c1
//   v72..v83 phase-2 rotating m/s pairs (3 sets of {m pair, s pair})
//   s[8:11] out SRD   s12,s13 soffsets   s[14:15] W1 ptr  s[16:17] b1 ptr
//   s[18:19] W2 ptr   s[20:21] active (w0,w1)  s22 beta  s[24:25] b2
//   s28 h counter  s[30:31] prefetched (w0,w1)  s[32:39]+s40 W1 row  s41 b1[h]

// 5-instr LIF step: mem = beta*mem + c; mem -= spk; spk = mem>1;
// acc_pair += (w0,w1) * broadcast(spk)   [op_sel_hi:[1,0,1] -> src0 hi half
// for high result, spk lo half for both halves]
#define TSTEP(LO,HI) \
  "v_fma_f32 v11, s22, v11, v10\n\t" \
  "v_sub_f32 v11, v11, v12\n\t" \
  "v_cmp_gt_f32 vcc, v11, 1.0\n\t" \
  "v_cndmask_b32 v12, 0, 1.0, vcc\n\t" \
  "v_pk_fma_f32 v[" #LO ":" #HI "], s[20:21], v[12:13], v[" #LO ":" #HI "] op_sel:[0,0,0] op_sel_hi:[1,0,1]\n\t"

// Phase-2 step t: c=acc[t]+b2; m_cur = beta*m_prev + c - s_prev; s_cur = m>1;
// store (s0,s1) and (m0,m1). vmcnt(4) ensures the stores that used cur's regs
// three steps ago have read their data out of the VGPRs.
#define P2STEP(ALO,AHI,MC0,MC1,SC0,SC1,MP0,MP1,SP0,SP1) \
  "s_waitcnt vmcnt(4)\n\t" \
  "v_add_f32 v66, s24, v" #ALO "\n\t" \
  "v_add_f32 v67, s25, v" #AHI "\n\t" \
  "v_fma_f32 v" #MC0 ", s22, v" #MP0 ", v66\n\t" \
  "v_sub_f32 v" #MC0 ", v" #MC0 ", v" #SP0 "\n\t" \
  "v_fma_f32 v" #MC1 ", s22, v" #MP1 ", v67\n\t" \
  "v_sub_f32 v" #MC1 ", v" #MC1 ", v" #SP1 "\n\t" \
  "v_cmp_gt_f32 vcc, v" #MC0 ", 1.0\n\t" \
  "v_cndmask_b32 v" #SC0 ", 0, 1.0, vcc\n\t" \
  "v_cmp_gt_f32 vcc, v" #MC1 ", 1.0\n\t" \
  "v_cndmask_b32 v" #SC1 ", 0, 1.0, vcc\n\t" \
  "buffer_store_dwordx2 v[" #SC0 ":" #SC1 "], v14, s[8:11], s12 offen\n\t" \
  "buffer_store_dwordx2 v[" #MC0 ":" #MC1 "], v14, s[8:11], s13 offen\n\t" \
  "s_add_u32 s12, s12, 0x200000\n\t" \
  "s_add_u32 s13, s13, 0x200000\n\t"

#define P2A(ALO,AHI) P2STEP(ALO,AHI,72,73,74,75,80,81,82,83)
#define P2B(ALO,AHI) P2STEP(ALO,AHI,76,77,78,79,72,73,74,75)
#define P2C(ALO,AHI) P2STEP(ALO,AHI,80,81,82,83,76,77,78,79)

#define ZV(N) "v_mov_b32 v" #N ", 0\n\t"

__global__
__attribute__((amdgpu_flat_work_group_size(256, 256), amdgpu_waves_per_eu(4, 4)))
void snn_fwd(
    const float* __restrict__ x,
    const float* __restrict__ W1,
    const float* __restrict__ b1,
    const float* __restrict__ W2,
    const float* __restrict__ b2,
    float* __restrict__ out)
{
    const int b = blockIdx.x * blockDim.x + threadIdx.x;

    float xi[NI];
#pragma unroll
    for (int i = 0; i < NI; ++i) xi[i] = x[(size_t)b * NI + i];

    asm volatile(
        // ---- preamble ----
        "s_mov_b64 s[14:15], %[pw1]\n\t"
        "s_mov_b64 s[16:17], %[pb1]\n\t"
        "s_mov_b64 s[18:19], %[pw2]\n\t"
        "s_mov_b64 s[8:9], %[pout]\n\t"
        "s_mov_b32 s10, -1\n\t"
        "s_mov_b32 s11, 0x00020000\n\t"
        "s_mov_b32 s12, 0\n\t"
        "s_mov_b32 s13, 0x3200000\n\t"
        "s_mov_b32 s22, 0x3f733333\n\t"
        "s_mov_b32 s28, 100\n\t"
        "s_load_dwordx2 s[24:25], %[pb2], 0x0\n\t"
        "s_load_dwordx8 s[32:39], s[14:15], 0x0\n\t"
        "s_load_dword s40, s[14:15], 0x20\n\t"
        "s_load_dword s41, s[16:17], 0x0\n\t"
        "s_load_dword s30, s[18:19], 0x0\n\t"
        "s_load_dword s31, s[18:19], 0x190\n\t"
        "v_lshlrev_b32 v14, 3, %[vb]\n\t"
        ZV(13)
        ZV(16) ZV(17) ZV(18) ZV(19) ZV(20) ZV(21) ZV(22) ZV(23) ZV(24) ZV(25)
        ZV(26) ZV(27) ZV(28) ZV(29) ZV(30) ZV(31) ZV(32) ZV(33) ZV(34) ZV(35)
        ZV(36) ZV(37) ZV(38) ZV(39) ZV(40) ZV(41) ZV(42) ZV(43) ZV(44) ZV(45)
        ZV(46) ZV(47) ZV(48) ZV(49) ZV(50) ZV(51) ZV(52) ZV(53) ZV(54) ZV(55)
        ZV(56) ZV(57) ZV(58) ZV(59) ZV(60) ZV(61) ZV(62) ZV(63) ZV(64) ZV(65)
        ZV(80) ZV(81) ZV(82) ZV(83)
        // ---- h loop ----
        "1:\n\t"
        "s_waitcnt lgkmcnt(0)\n\t"
        "s_mov_b64 s[20:21], s[30:31]\n\t"
        "v_mul_f32 v10, s32, %[x0]\n\t"
        "v_fma_f32 v10, s33, %[x1], v10\n\t"
        "v_fma_f32 v10, s34, %[x2], v10\n\t"
        "v_fma_f32 v10, s35, %[x3], v10\n\t"
        "v_fma_f32 v10, s36, %[x4], v10\n\t"
        "v_fma_f32 v10, s37, %[x5], v10\n\t"
        "v_fma_f32 v10, s38, %[x6], v10\n\t"
        "v_fma_f32 v10, s39, %[x7], v10\n\t"
        "v_fma_f32 v10, s40, %[x8], v10\n\t"
        "v_add_f32 v10, s41, v10\n\t"
        // prefetch next h's weights (skip on last iteration: OOB guard)
        "s_cmp_lg_u32 s28, 1\n\t"
        "s_cbranch_scc0 2f\n\t"
        "s_add_u32 s14, s14, 36\n\t"
        "s_addc_u32 s15, s15, 0\n\t"
        "s_add_u32 s16, s16, 4\n\t"
        "s_addc_u32 s17, s17, 0\n\t"
        "s_add_u32 s18, s18, 4\n\t"
        "s_addc_u32 s19, s19, 0\n\t"
        "s_load_dwordx8 s[32:39], s[14:15], 0x0\n\t"
        "s_load_dword s40, s[14:15], 0x20\n\t"
        "s_load_dword s41, s[16:17], 0x0\n\t"
        "s_load_dword s30, s[18:19], 0x0\n\t"
        "s_load_dword s31, s[18:19], 0x190\n\t"
        "2:\n\t"
        "v_mov_b32 v11, 0\n\t"
        "v_mov_b32 v12, 0\n\t"
        TSTEP(16,17) TSTEP(18,19) TSTEP(20,21) TSTEP(22,23) TSTEP(24,25)
        TSTEP(26,27) TSTEP(28,29) TSTEP(30,31) TSTEP(32,33) TSTEP(34,35)
        TSTEP(36,37) TSTEP(38,39) TSTEP(40,41) TSTEP(42,43) TSTEP(44,45)
        TSTEP(46,47) TSTEP(48,49) TSTEP(50,51) TSTEP(52,53) TSTEP(54,55)
        TSTEP(56,57) TSTEP(58,59) TSTEP(60,61) TSTEP(62,63) TSTEP(64,65)
        "s_sub_u32 s28, s28, 1\n\t"
        "s_cmp_lg_u32 s28, 0\n\t"
        "s_cbranch_scc1 1b\n\t"
        // ---- phase 2: output LIF + stores ----
        P2A(16,17) P2B(18,19) P2C(20,21)
        P2A(22,23) P2B(24,25) P2C(26,27)
        P2A(28,29) P2B(30,31) P2C(32,33)
        P2A(34,35) P2B(36,37) P2C(38,39)
        P2A(40,41) P2B(42,43) P2C(44,45)
        P2A(46,47) P2B(48,49) P2C(50,51)
        P2A(52,53) P2B(54,55) P2C(56,57)
        P2A(58,59) P2B(60,61) P2C(62,63)
        P2A(64,65)
        :
        : [pw1]"s"(W1), [pb1]"s"(b1), [pw2]"s"(W2), [pb2]"s"(b2),
          [pout]"s"(out),
          [x0]"v"(xi[0]), [x1]"v"(xi[1]), [x2]"v"(xi[2]), [x3]"v"(xi[3]),
          [x4]"v"(xi[4]), [x5]"v"(xi[5]), [x6]"v"(xi[6]), [x7]"v"(xi[7]),
          [x8]"v"(xi[8]), [vb]"v"(b)
        : "s8","s9","s10","s11","s12","s13","s14","s15","s16","s17","s18","s19",
          "s20","s21","s22","s23","s24","s25","s26","s27","s28","s29","s30",
          "s31","s32","s33","s34","s35","s36","s37","s38","s39","s40","s41",
          "v10","v11","v12","v13","v14","v15",
          "v16","v17","v18","v19","v20","v21","v22","v23","v24","v25","v26",
          "v27","v28","v29","v30","v31","v32","v33","v34","v35","v36","v37",
          "v38","v39","v40","v41","v42","v43","v44","v45","v46","v47","v48",
          "v49","v50","v51","v52","v53","v54","v55","v56","v57","v58","v59",
          "v60","v61","v62","v63","v64","v65","v66","v67",
          "v72","v73","v74","v75","v76","v77","v78","v79","v80","v81","v82","v83",
          "vcc","scc","memory");
}

extern "C" void kernel_launch(void* const* d_in, const int* in_sizes, int n_in,
                              void* d_out, int out_size, void* d_ws, size_t ws_size,
                              hipStream_t stream) {
    const float* x  = (const float*)d_in[0];
    const float* W1 = (const float*)d_in[1];
    const float* b1 = (const float*)d_in[2];
    const float* W2 = (const float*)d_in[3];
    const float* b2 = (const float*)d_in[4];
    float* out = (float*)d_out;

    dim3 block(256);
    dim3 grid(BATCH / 256);
    snn_fwd<<<grid, block, 0, stream>>>(x, W1, b1, W2, b2, out);
}

// Round 5
// 195.321 us; speedup vs baseline: 1.0450x; 1.0450x over previous
//
#include <hip/hip_runtime.h>

#define BATCH 262144
#define NI 9
#define NH 100
#define NO 2
#define T 25

// One thread per batch element. Entire hot path is one fixed-register asm
// block (R1-R3: compiler parks the 50 per-step accumulators in AGPRs and pays
// v_accvgpr round-trips per update; R4: v_pk_fma_f32 turned out to issue at
// ~12-16 cyc on gfx950 -> replaced with two scalar v_fmac_f32 at 2 cyc each).
//
// Register map (all clobbered):
//   v10 c      v11 mem    v12 spk    v14 store voffset (b*8)
//   v[16+2t : 17+2t] t=0..24 : acc pair (acc0[t], acc1[t])
//   v66,v67 phase-2 c0,c1
//   v72..v83 phase-2 rotating m/s pairs (3 sets of {m pair, s pair})
//   s[8:11] out SRD   s12,s13 soffsets   s[14:15] W1 ptr  s[16:17] b1 ptr
//   s[18:19] W2 ptr   s[20:21] active (w0,w1)  s22 beta  s[24:25] b2
//   s28 h counter  s[30:31] prefetched (w0,w1)  s[32:39]+s40 W1 row  s41 b1[h]

// 6-instr LIF step, all full-rate scalar VALU (2 cyc each):
// mem = beta*mem + c; mem -= spk; spk = mem>1; acc0 += w0*spk; acc1 += w1*spk
#define TSTEP(LO,HI) \
  "v_fma_f32 v11, s22, v11, v10\n\t" \
  "v_sub_f32 v11, v11, v12\n\t" \
  "v_cmp_gt_f32 vcc, v11, 1.0\n\t" \
  "v_cndmask_b32 v12, 0, 1.0, vcc\n\t" \
  "v_fmac_f32 v" #LO ", s20, v12\n\t" \
  "v_fmac_f32 v" #HI ", s21, v12\n\t"

// Phase-2 step t: c=acc[t]+b2; m_cur = beta*m_prev + c - s_prev; s_cur = m>1;
// store (s0,s1) and (m0,m1). vmcnt(4) ensures the stores that used cur's regs
// three steps ago have read their data out of the VGPRs.
#define P2STEP(ALO,AHI,MC0,MC1,SC0,SC1,MP0,MP1,SP0,SP1) \
  "s_waitcnt vmcnt(4)\n\t" \
  "v_add_f32 v66, s24, v" #ALO "\n\t" \
  "v_add_f32 v67, s25, v" #AHI "\n\t" \
  "v_fma_f32 v" #MC0 ", s22, v" #MP0 ", v66\n\t" \
  "v_sub_f32 v" #MC0 ", v" #MC0 ", v" #SP0 "\n\t" \
  "v_fma_f32 v" #MC1 ", s22, v" #MP1 ", v67\n\t" \
  "v_sub_f32 v" #MC1 ", v" #MC1 ", v" #SP1 "\n\t" \
  "v_cmp_gt_f32 vcc, v" #MC0 ", 1.0\n\t" \
  "v_cndmask_b32 v" #SC0 ", 0, 1.0, vcc\n\t" \
  "v_cmp_gt_f32 vcc, v" #MC1 ", 1.0\n\t" \
  "v_cndmask_b32 v" #SC1 ", 0, 1.0, vcc\n\t" \
  "buffer_store_dwordx2 v[" #SC0 ":" #SC1 "], v14, s[8:11], s12 offen\n\t" \
  "buffer_store_dwordx2 v[" #MC0 ":" #MC1 "], v14, s[8:11], s13 offen\n\t" \
  "s_add_u32 s12, s12, 0x200000\n\t" \
  "s_add_u32 s13, s13, 0x200000\n\t"

#define P2A(ALO,AHI) P2STEP(ALO,AHI,72,73,74,75,80,81,82,83)
#define P2B(ALO,AHI) P2STEP(ALO,AHI,76,77,78,79,72,73,74,75)
#define P2C(ALO,AHI) P2STEP(ALO,AHI,80,81,82,83,76,77,78,79)

#define ZV(N) "v_mov_b32 v" #N ", 0\n\t"

__global__
__attribute__((amdgpu_flat_work_group_size(256, 256), amdgpu_waves_per_eu(4, 4)))
void snn_fwd(
    const float* __restrict__ x,
    const float* __restrict__ W1,
    const float* __restrict__ b1,
    const float* __restrict__ W2,
    const float* __restrict__ b2,
    float* __restrict__ out)
{
    const int b = blockIdx.x * blockDim.x + threadIdx.x;

    float xi[NI];
#pragma unroll
    for (int i = 0; i < NI; ++i) xi[i] = x[(size_t)b * NI + i];

    asm volatile(
        // ---- preamble ----
        "s_mov_b64 s[14:15], %[pw1]\n\t"
        "s_mov_b64 s[16:17], %[pb1]\n\t"
        "s_mov_b64 s[18:19], %[pw2]\n\t"
        "s_mov_b64 s[8:9], %[pout]\n\t"
        "s_mov_b32 s10, -1\n\t"
        "s_mov_b32 s11, 0x00020000\n\t"
        "s_mov_b32 s12, 0\n\t"
        "s_mov_b32 s13, 0x3200000\n\t"
        "s_mov_b32 s22, 0x3f733333\n\t"
        "s_mov_b32 s28, 100\n\t"
        "s_load_dwordx2 s[24:25], %[pb2], 0x0\n\t"
        "s_load_dwordx8 s[32:39], s[14:15], 0x0\n\t"
        "s_load_dword s40, s[14:15], 0x20\n\t"
        "s_load_dword s41, s[16:17], 0x0\n\t"
        "s_load_dword s30, s[18:19], 0x0\n\t"
        "s_load_dword s31, s[18:19], 0x190\n\t"
        "v_lshlrev_b32 v14, 3, %[vb]\n\t"
        ZV(16) ZV(17) ZV(18) ZV(19) ZV(20) ZV(21) ZV(22) ZV(23) ZV(24) ZV(25)
        ZV(26) ZV(27) ZV(28) ZV(29) ZV(30) ZV(31) ZV(32) ZV(33) ZV(34) ZV(35)
        ZV(36) ZV(37) ZV(38) ZV(39) ZV(40) ZV(41) ZV(42) ZV(43) ZV(44) ZV(45)
        ZV(46) ZV(47) ZV(48) ZV(49) ZV(50) ZV(51) ZV(52) ZV(53) ZV(54) ZV(55)
        ZV(56) ZV(57) ZV(58) ZV(59) ZV(60) ZV(61) ZV(62) ZV(63) ZV(64) ZV(65)
        ZV(80) ZV(81) ZV(82) ZV(83)
        // ---- h loop ----
        "1:\n\t"
        "s_waitcnt lgkmcnt(0)\n\t"
        "s_mov_b64 s[20:21], s[30:31]\n\t"
        "v_mul_f32 v10, s32, %[x0]\n\t"
        "v_fma_f32 v10, s33, %[x1], v10\n\t"
        "v_fma_f32 v10, s34, %[x2], v10\n\t"
        "v_fma_f32 v10, s35, %[x3], v10\n\t"
        "v_fma_f32 v10, s36, %[x4], v10\n\t"
        "v_fma_f32 v10, s37, %[x5], v10\n\t"
        "v_fma_f32 v10, s38, %[x6], v10\n\t"
        "v_fma_f32 v10, s39, %[x7], v10\n\t"
        "v_fma_f32 v10, s40, %[x8], v10\n\t"
        "v_add_f32 v10, s41, v10\n\t"
        // prefetch next h's weights (skip on last iteration: OOB guard)
        "s_cmp_lg_u32 s28, 1\n\t"
        "s_cbranch_scc0 2f\n\t"
        "s_add_u32 s14, s14, 36\n\t"
        "s_addc_u32 s15, s15, 0\n\t"
        "s_add_u32 s16, s16, 4\n\t"
        "s_addc_u32 s17, s17, 0\n\t"
        "s_add_u32 s18, s18, 4\n\t"
        "s_addc_u32 s19, s19, 0\n\t"
        "s_load_dwordx8 s[32:39], s[14:15], 0x0\n\t"
        "s_load_dword s40, s[14:15], 0x20\n\t"
        "s_load_dword s41, s[16:17], 0x0\n\t"
        "s_load_dword s30, s[18:19], 0x0\n\t"
        "s_load_dword s31, s[18:19], 0x190\n\t"
        "2:\n\t"
        "v_mov_b32 v11, 0\n\t"
        "v_mov_b32 v12, 0\n\t"
        TSTEP(16,17) TSTEP(18,19) TSTEP(20,21) TSTEP(22,23) TSTEP(24,25)
        TSTEP(26,27) TSTEP(28,29) TSTEP(30,31) TSTEP(32,33) TSTEP(34,35)
        TSTEP(36,37) TSTEP(38,39) TSTEP(40,41) TSTEP(42,43) TSTEP(44,45)
        TSTEP(46,47) TSTEP(48,49) TSTEP(50,51) TSTEP(52,53) TSTEP(54,55)
        TSTEP(56,57) TSTEP(58,59) TSTEP(60,61) TSTEP(62,63) TSTEP(64,65)
        "s_sub_u32 s28, s28, 1\n\t"
        "s_cmp_lg_u32 s28, 0\n\t"
        "s_cbranch_scc1 1b\n\t"
        // ---- phase 2: output LIF + stores ----
        P2A(16,17) P2B(18,19) P2C(20,21)
        P2A(22,23) P2B(24,25) P2C(26,27)
        P2A(28,29) P2B(30,31) P2C(32,33)
        P2A(34,35) P2B(36,37) P2C(38,39)
        P2A(40,41) P2B(42,43) P2C(44,45)
        P2A(46,47) P2B(48,49) P2C(50,51)
        P2A(52,53) P2B(54,55) P2C(56,57)
        P2A(58,59) P2B(60,61) P2C(62,63)
        P2A(64,65)
        :
        : [pw1]"s"(W1), [pb1]"s"(b1), [pw2]"s"(W2), [pb2]"s"(b2),
          [pout]"s"(out),
          [x0]"v"(xi[0]), [x1]"v"(xi[1]), [x2]"v"(xi[2]), [x3]"v"(xi[3]),
          [x4]"v"(xi[4]), [x5]"v"(xi[5]), [x6]"v"(xi[6]), [x7]"v"(xi[7]),
          [x8]"v"(xi[8]), [vb]"v"(b)
        : "s8","s9","s10","s11","s12","s13","s14","s15","s16","s17","s18","s19",
          "s20","s21","s22","s23","s24","s25","s26","s27","s28","s29","s30",
          "s31","s32","s33","s34","s35","s36","s37","s38","s39","s40","s41",
          "v10","v11","v12","v13","v14","v15",
          "v16","v17","v18","v19","v20","v21","v22","v23","v24","v25","v26",
          "v27","v28","v29","v30","v31","v32","v33","v34","v35","v36","v37",
          "v38","v39","v40","v41","v42","v43","v44","v45","v46","v47","v48",
          "v49","v50","v51","v52","v53","v54","v55","v56","v57","v58","v59",
          "v60","v61","v62","v63","v64","v65","v66","v67",
          "v72","v73","v74","v75","v76","v77","v78","v79","v80","v81","v82","v83",
          "vcc","scc","memory");
}

extern "C" void kernel_launch(void* const* d_in, const int* in_sizes, int n_in,
                              void* d_out, int out_size, void* d_ws, size_t ws_size,
                              hipStream_t stream) {
    const float* x  = (const float*)d_in[0];
    const float* W1 = (const float*)d_in[1];
    const float* b1 = (const float*)d_in[2];
    const float* W2 = (const float*)d_in[3];
    const float* b2 = (const float*)d_in[4];
    float* out = (float*)d_out;

    dim3 block(256);
    dim3 grid(BATCH / 256);
    snn_fwd<<<grid, block, 0, stream>>>(x, W1, b1, W2, b2, out);
}

// Round 7
// 182.951 us; speedup vs baseline: 1.1156x; 1.0676x over previous
//
#include <hip/hip_runtime.h>

#define BATCH 262144
#define NI 9
#define NH 100
#define NO 2
#define T 25

// One thread per batch element, whole hot path in one fixed-register asm block.
// R7: all TSTEP ops converted to 3-src FMA-family (model: fma-class ~3 cyc,
// VOP2/VOPC ~4 cyc on gfx950; R5 mix measured 3.87 cyc/instr, pure-fma 3.05):
//   mem = fma(beta, mem, c); mem = fmac(-1.0, spk)        [== sub, bit-exact]
//   pre = fma(K, mem, -K)   K=2^60: exact 0 iff mem==1, else |pre|>=2^36
//   spk = med3(pre, 0, 1.0)  == (mem>1)?1:0 bit-exact (incl. mem==1 -> 0)
//   acc0 += w0*spk; acc1 += w1*spk
// Never-spike skip (exact): all-lane c <= 0.048828125 -> sup mem = 14.45*c
// < 0.71 < 1 -> t-loop is provably spike-free, fmacs would add +0.0 -> skip.
//
// Register map: v9 pre, v10 c, v11 mem, v12 spk, v14 store voffset,
// v[16+2t:17+2t] acc pairs, v66..v83 phase-2. s[8:11] out SRD, s12/s13
// soffsets, s[14:15] W1, s[16:17] b1, s[18:19] W2, s[20:21] w-pair, s22 beta,
// s[24:25] b2, s28 h-counter, s29 K, s[30:31] prefetch w-pair, s[32:40] W1row,
// s41 b1[h].

#define TSTEP(LO,HI) \
  "v_fma_f32 v11, s22, v11, v10\n\t" \
  "v_fmac_f32 v11, -1.0, v12\n\t" \
  "v_fma_f32 v9, s29, v11, -s29\n\t" \
  "v_med3_f32 v12, v9, 0, 1.0\n\t" \
  "v_fmac_f32 v" #LO ", s20, v12\n\t" \
  "v_fmac_f32 v" #HI ", s21, v12\n\t"

// Phase-2 step (unchanged from R5, which passed): rotating m/s register sets,
// vmcnt(4) guards VGPR reuse while stores are in flight.
#define P2STEP(ALO,AHI,MC0,MC1,SC0,SC1,MP0,MP1,SP0,SP1) \
  "s_waitcnt vmcnt(4)\n\t" \
  "v_add_f32 v66, s24, v" #ALO "\n\t" \
  "v_add_f32 v67, s25, v" #AHI "\n\t" \
  "v_fma_f32 v" #MC0 ", s22, v" #MP0 ", v66\n\t" \
  "v_sub_f32 v" #MC0 ", v" #MC0 ", v" #SP0 "\n\t" \
  "v_fma_f32 v" #MC1 ", s22, v" #MP1 ", v67\n\t" \
  "v_sub_f32 v" #MC1 ", v" #MC1 ", v" #SP1 "\n\t" \
  "v_cmp_gt_f32 vcc, v" #MC0 ", 1.0\n\t" \
  "v_cndmask_b32 v" #SC0 ", 0, 1.0, vcc\n\t" \
  "v_cmp_gt_f32 vcc, v" #MC1 ", 1.0\n\t" \
  "v_cndmask_b32 v" #SC1 ", 0, 1.0, vcc\n\t" \
  "buffer_store_dwordx2 v[" #SC0 ":" #SC1 "], v14, s[8:11], s12 offen\n\t" \
  "buffer_store_dwordx2 v[" #MC0 ":" #MC1 "], v14, s[8:11], s13 offen\n\t" \
  "s_add_u32 s12, s12, 0x200000\n\t" \
  "s_add_u32 s13, s13, 0x200000\n\t"

#define P2A(ALO,AHI) P2STEP(ALO,AHI,72,73,74,75,80,81,82,83)
#define P2B(ALO,AHI) P2STEP(ALO,AHI,76,77,78,79,72,73,74,75)
#define P2C(ALO,AHI) P2STEP(ALO,AHI,80,81,82,83,76,77,78,79)

#define ZV(N) "v_mov_b32 v" #N ", 0\n\t"

__global__
__attribute__((amdgpu_flat_work_group_size(256, 256), amdgpu_waves_per_eu(4, 4)))
void snn_fwd(
    const float* __restrict__ x,
    const float* __restrict__ W1,
    const float* __restrict__ b1,
    const float* __restrict__ W2,
    const float* __restrict__ b2,
    float* __restrict__ out)
{
    const int b = blockIdx.x * blockDim.x + threadIdx.x;

    float xi[NI];
#pragma unroll
    for (int i = 0; i < NI; ++i) xi[i] = x[(size_t)b * NI + i];

    asm volatile(
        // ---- preamble ----
        "s_mov_b64 s[14:15], %[pw1]\n\t"
        "s_mov_b64 s[16:17], %[pb1]\n\t"
        "s_mov_b64 s[18:19], %[pw2]\n\t"
        "s_mov_b64 s[8:9], %[pout]\n\t"
        "s_mov_b32 s10, -1\n\t"
        "s_mov_b32 s11, 0x00020000\n\t"
        "s_mov_b32 s12, 0\n\t"
        "s_mov_b32 s13, 0x3200000\n\t"
        "s_mov_b32 s22, 0x3f733333\n\t"   // beta = 0.95f
        "s_mov_b32 s29, 0x5d800000\n\t"   // K = 2^60
        "s_mov_b32 s28, 100\n\t"
        "s_load_dwordx2 s[24:25], %[pb2], 0x0\n\t"
        "s_load_dwordx8 s[32:39], s[14:15], 0x0\n\t"
        "s_load_dword s40, s[14:15], 0x20\n\t"
        "s_load_dword s41, s[16:17], 0x0\n\t"
        "s_load_dword s30, s[18:19], 0x0\n\t"
        "s_load_dword s31, s[18:19], 0x190\n\t"
        "v_lshlrev_b32 v14, 3, %[vb]\n\t"
        ZV(16) ZV(17) ZV(18) ZV(19) ZV(20) ZV(21) ZV(22) ZV(23) ZV(24) ZV(25)
        ZV(26) ZV(27) ZV(28) ZV(29) ZV(30) ZV(31) ZV(32) ZV(33) ZV(34) ZV(35)
        ZV(36) ZV(37) ZV(38) ZV(39) ZV(40) ZV(41) ZV(42) ZV(43) ZV(44) ZV(45)
        ZV(46) ZV(47) ZV(48) ZV(49) ZV(50) ZV(51) ZV(52) ZV(53) ZV(54) ZV(55)
        ZV(56) ZV(57) ZV(58) ZV(59) ZV(60) ZV(61) ZV(62) ZV(63) ZV(64) ZV(65)
        ZV(80) ZV(81) ZV(82) ZV(83)
        // ---- h loop ----
        "1:\n\t"
        "s_waitcnt lgkmcnt(0)\n\t"
        "s_mov_b64 s[20:21], s[30:31]\n\t"
        "v_mul_f32 v10, s32, %[x0]\n\t"
        "v_fma_f32 v10, s33, %[x1], v10\n\t"
        "v_fma_f32 v10, s34, %[x2], v10\n\t"
        "v_fma_f32 v10, s35, %[x3], v10\n\t"
        "v_fma_f32 v10, s36, %[x4], v10\n\t"
        "v_fma_f32 v10, s37, %[x5], v10\n\t"
        "v_fma_f32 v10, s38, %[x6], v10\n\t"
        "v_fma_f32 v10, s39, %[x7], v10\n\t"
        "v_fma_f32 v10, s40, %[x8], v10\n\t"
        "v_add_f32 v10, s41, v10\n\t"
        // prefetch next h's weights (skip on last iteration: OOB guard)
        "s_cmp_lg_u32 s28, 1\n\t"
        "s_cbranch_scc0 2f\n\t"
        "s_add_u32 s14, s14, 36\n\t"
        "s_addc_u32 s15, s15, 0\n\t"
        "s_add_u32 s16, s16, 4\n\t"
        "s_addc_u32 s17, s17, 0\n\t"
        "s_add_u32 s18, s18, 4\n\t"
        "s_addc_u32 s19, s19, 0\n\t"
        "s_load_dwordx8 s[32:39], s[14:15], 0x0\n\t"
        "s_load_dword s40, s[14:15], 0x20\n\t"
        "s_load_dword s41, s[16:17], 0x0\n\t"
        "s_load_dword s30, s[18:19], 0x0\n\t"
        "s_load_dword s31, s[18:19], 0x190\n\t"
        "2:\n\t"
        // never-spike skip: no lane with c > 0.048828125 -> t-loop is a no-op
        "v_cmp_lt_f32 vcc, 0x3d480000, v10\n\t"
        "s_nop 1\n\t"
        "s_cbranch_vccz 3f\n\t"
        "v_mov_b32 v11, 0\n\t"
        "v_mov_b32 v12, 0\n\t"
        TSTEP(16,17) TSTEP(18,19) TSTEP(20,21) TSTEP(22,23) TSTEP(24,25)
        TSTEP(26,27) TSTEP(28,29) TSTEP(30,31) TSTEP(32,33) TSTEP(34,35)
        TSTEP(36,37) TSTEP(38,39) TSTEP(40,41) TSTEP(42,43) TSTEP(44,45)
        TSTEP(46,47) TSTEP(48,49) TSTEP(50,51) TSTEP(52,53) TSTEP(54,55)
        TSTEP(56,57) TSTEP(58,59) TSTEP(60,61) TSTEP(62,63) TSTEP(64,65)
        "3:\n\t"
        "s_sub_u32 s28, s28, 1\n\t"
        "s_cmp_lg_u32 s28, 0\n\t"
        "s_cbranch_scc1 1b\n\t"
        // ---- phase 2: output LIF + stores ----
        P2A(16,17) P2B(18,19) P2C(20,21)
        P2A(22,23) P2B(24,25) P2C(26,27)
        P2A(28,29) P2B(30,31) P2C(32,33)
        P2A(34,35) P2B(36,37) P2C(38,39)
        P2A(40,41) P2B(42,43) P2C(44,45)
        P2A(46,47) P2B(48,49) P2C(50,51)
        P2A(52,53) P2B(54,55) P2C(56,57)
        P2A(58,59) P2B(60,61) P2C(62,63)
        P2A(64,65)
        :
        : [pw1]"s"(W1), [pb1]"s"(b1), [pw2]"s"(W2), [pb2]"s"(b2),
          [pout]"s"(out),
          [x0]"v"(xi[0]), [x1]"v"(xi[1]), [x2]"v"(xi[2]), [x3]"v"(xi[3]),
          [x4]"v"(xi[4]), [x5]"v"(xi[5]), [x6]"v"(xi[6]), [x7]"v"(xi[7]),
          [x8]"v"(xi[8]), [vb]"v"(b)
        : "s8","s9","s10","s11","s12","s13","s14","s15","s16","s17","s18","s19",
          "s20","s21","s22","s23","s24","s25","s26","s27","s28","s29","s30",
          "s31","s32","s33","s34","s35","s36","s37","s38","s39","s40","s41",
          "v9","v10","v11","v12","v13","v14","v15",
          "v16","v17","v18","v19","v20","v21","v22","v23","v24","v25","v26",
          "v27","v28","v29","v30","v31","v32","v33","v34","v35","v36","v37",
          "v38","v39","v40","v41","v42","v43","v44","v45","v46","v47","v48",
          "v49","v50","v51","v52","v53","v54","v55","v56","v57","v58","v59",
          "v60","v61","v62","v63","v64","v65","v66","v67",
          "v72","v73","v74","v75","v76","v77","v78","v79","v80","v81","v82","v83",
          "vcc","scc","memory");
}

extern "C" void kernel_launch(void* const* d_in, const int* in_sizes, int n_in,
                              void* d_out, int out_size, void* d_ws, size_t ws_size,
                              hipStream_t stream) {
    const float* x  = (const float*)d_in[0];
    const float* W1 = (const float*)d_in[1];
    const float* b1 = (const float*)d_in[2];
    const float* W2 = (const float*)d_in[3];
    const float* b2 = (const float*)d_in[4];
    float* out = (float*)d_out;

    dim3 block(256);
    dim3 grid(BATCH / 256);
    snn_fwd<<<grid, block, 0, stream>>>(x, W1, b1, W2, b2, out);
}

// Round 9
// 177.011 us; speedup vs baseline: 1.1531x; 1.0336x over previous
//
#include <hip/hip_runtime.h>

#define BATCH 262144
#define NI 9
#define NH 100
#define NO 2
#define T 25

// R9 (= R8 design, compile-fixed): 2 threads per element (h-split 50/50) ->
// 8192 waves (~6-7/SIMD) vs the structural 4 of 1-thread-per-element.
// half is derived from the WAVE index ((tid>>6)&1) so it is wave-uniform;
// __builtin_amdgcn_readfirstlane makes it compiler-visibly uniform so the
// h-partition pointers stay in SGPRs and the "s" asm constraints hold
// (R8's compile failure: divergent pointer -> VGPR pair -> s_mov_b64 s,v).
// Fixed asm SGPRs moved to s40..s62, clear of reserved s30-s35 (R8 error).
// Asm owns ONLY the h-loop; accs are "+v" operands (arch VGPRs guaranteed);
// LDS reduction, phase 2, stores are plain HIP.
// Per-step math bit-identical to R7 (passed, absmax 0.03125):
//   mem = fma(beta,mem,c); mem = fmac(-1,spk); pre = fma(K,mem,-K) K=2^60;
//   spk = med3(pre,0,1) [== (mem>1)?1:0 exactly]; acc += w*spk (x2)
// Never-spike skip (exact): all-lane c <= 0.048828125 -> sup mem < 0.71 < 1.
// Known numeric delta: cur2 = fold(h0..49)+fold(h50..99) (~1 ulp, journaled).

#define TSTEP(t) \
  "v_fma_f32 v1, s46, v1, v0\n\t" \
  "v_fmac_f32 v1, -1.0, v2\n\t" \
  "v_fma_f32 v3, s47, v1, -s47\n\t" \
  "v_med3_f32 v2, v3, 0, 1.0\n\t" \
  "v_fmac_f32 %[a" #t "x], s60, v2\n\t" \
  "v_fmac_f32 %[a" #t "y], s61, v2\n\t"

__global__
__attribute__((amdgpu_flat_work_group_size(256, 256), amdgpu_waves_per_eu(6, 8)))
void snn_fwd(
    const float* __restrict__ x,
    const float* __restrict__ W1,
    const float* __restrict__ b1,
    const float* __restrict__ W2,
    const float* __restrict__ b2,
    float* __restrict__ out)
{
    __shared__ float2 red[13 * 128];   // 13 t-slots x 128 elems = 13312 B

    const int tid  = threadIdx.x;
    const int lane = tid & 63;
    const int w    = tid >> 6;
    const int half = __builtin_amdgcn_readfirstlane(w & 1);  // wave-uniform
    const int el   = (w >> 1) * 64 + lane;                   // 0..127
    const int e    = blockIdx.x * 128 + el;

    float xi[NI];
#pragma unroll
    for (int i = 0; i < NI; ++i) xi[i] = x[(size_t)e * NI + i];

    float acc0[T], acc1[T];
#pragma unroll
    for (int t = 0; t < T; ++t) { acc0[t] = 0.0f; acc1[t] = 0.0f; }

    // Uniform (SGPR) h-partition pointers.
    const float* W1h = W1 + half * 50 * NI;
    const float* b1h = b1 + half * 50;
    const float* W2h = W2 + half * 50;   // W2[1,h] at byte offset +0x190

    asm volatile(
        "s_mov_b64 s[40:41], %[pw1]\n\t"
        "s_mov_b64 s[42:43], %[pb1]\n\t"
        "s_mov_b64 s[44:45], %[pw2]\n\t"
        "s_mov_b32 s46, 0x3f733333\n\t"   // beta
        "s_mov_b32 s47, 0x5d800000\n\t"   // K = 2^60
        "s_mov_b32 s62, 50\n\t"           // h counter
        "s_load_dwordx8 s[48:55], s[40:41], 0x0\n\t"
        "s_load_dword s56, s[40:41], 0x20\n\t"
        "s_load_dword s57, s[42:43], 0x0\n\t"
        "s_load_dword s58, s[44:45], 0x0\n\t"
        "s_load_dword s59, s[44:45], 0x190\n\t"
        "1:\n\t"
        "s_waitcnt lgkmcnt(0)\n\t"
        "s_mov_b64 s[60:61], s[58:59]\n\t"
        "v_mul_f32 v0, s48, %[x0]\n\t"
        "v_fma_f32 v0, s49, %[x1], v0\n\t"
        "v_fma_f32 v0, s50, %[x2], v0\n\t"
        "v_fma_f32 v0, s51, %[x3], v0\n\t"
        "v_fma_f32 v0, s52, %[x4], v0\n\t"
        "v_fma_f32 v0, s53, %[x5], v0\n\t"
        "v_fma_f32 v0, s54, %[x6], v0\n\t"
        "v_fma_f32 v0, s55, %[x7], v0\n\t"
        "v_fma_f32 v0, s56, %[x8], v0\n\t"
        "v_add_f32 v0, s57, v0\n\t"
        // prefetch next h's weights (skip on last iteration)
        "s_cmp_lg_u32 s62, 1\n\t"
        "s_cbranch_scc0 2f\n\t"
        "s_add_u32 s40, s40, 36\n\t"
        "s_addc_u32 s41, s41, 0\n\t"
        "s_add_u32 s42, s42, 4\n\t"
        "s_addc_u32 s43, s43, 0\n\t"
        "s_add_u32 s44, s44, 4\n\t"
        "s_addc_u32 s45, s45, 0\n\t"
        "s_load_dwordx8 s[48:55], s[40:41], 0x0\n\t"
        "s_load_dword s56, s[40:41], 0x20\n\t"
        "s_load_dword s57, s[42:43], 0x0\n\t"
        "s_load_dword s58, s[44:45], 0x0\n\t"
        "s_load_dword s59, s[44:45], 0x190\n\t"
        "2:\n\t"
        // never-spike skip: no lane with c > 0.048828125 -> t-loop is a no-op
        "v_cmp_lt_f32 vcc, 0x3d480000, v0\n\t"
        "s_cbranch_vccz 3f\n\t"
        "v_mov_b32 v1, 0\n\t"
        "v_mov_b32 v2, 0\n\t"
        TSTEP(0)  TSTEP(1)  TSTEP(2)  TSTEP(3)  TSTEP(4)
        TSTEP(5)  TSTEP(6)  TSTEP(7)  TSTEP(8)  TSTEP(9)
        TSTEP(10) TSTEP(11) TSTEP(12) TSTEP(13) TSTEP(14)
        TSTEP(15) TSTEP(16) TSTEP(17) TSTEP(18) TSTEP(19)
        TSTEP(20) TSTEP(21) TSTEP(22) TSTEP(23) TSTEP(24)
        "3:\n\t"
        "s_sub_u32 s62, s62, 1\n\t"
        "s_cmp_lg_u32 s62, 0\n\t"
        "s_cbranch_scc1 1b\n\t"
        : [a0x]"+v"(acc0[0]),  [a0y]"+v"(acc1[0]),
          [a1x]"+v"(acc0[1]),  [a1y]"+v"(acc1[1]),
          [a2x]"+v"(acc0[2]),  [a2y]"+v"(acc1[2]),
          [a3x]"+v"(acc0[3]),  [a3y]"+v"(acc1[3]),
          [a4x]"+v"(acc0[4]),  [a4y]"+v"(acc1[4]),
          [a5x]"+v"(acc0[5]),  [a5y]"+v"(acc1[5]),
          [a6x]"+v"(acc0[6]),  [a6y]"+v"(acc1[6]),
          [a7x]"+v"(acc0[7]),  [a7y]"+v"(acc1[7]),
          [a8x]"+v"(acc0[8]),  [a8y]"+v"(acc1[8]),
          [a9x]"+v"(acc0[9]),  [a9y]"+v"(acc1[9]),
          [a10x]"+v"(acc0[10]), [a10y]"+v"(acc1[10]),
          [a11x]"+v"(acc0[11]), [a11y]"+v"(acc1[11]),
          [a12x]"+v"(acc0[12]), [a12y]"+v"(acc1[12]),
          [a13x]"+v"(acc0[13]), [a13y]"+v"(acc1[13]),
          [a14x]"+v"(acc0[14]), [a14y]"+v"(acc1[14]),
          [a15x]"+v"(acc0[15]), [a15y]"+v"(acc1[15]),
          [a16x]"+v"(acc0[16]), [a16y]"+v"(acc1[16]),
          [a17x]"+v"(acc0[17]), [a17y]"+v"(acc1[17]),
          [a18x]"+v"(acc0[18]), [a18y]"+v"(acc1[18]),
          [a19x]"+v"(acc0[19]), [a19y]"+v"(acc1[19]),
          [a20x]"+v"(acc0[20]), [a20y]"+v"(acc1[20]),
          [a21x]"+v"(acc0[21]), [a21y]"+v"(acc1[21]),
          [a22x]"+v"(acc0[22]), [a22y]"+v"(acc1[22]),
          [a23x]"+v"(acc0[23]), [a23y]"+v"(acc1[23]),
          [a24x]"+v"(acc0[24]), [a24y]"+v"(acc1[24])
        : [pw1]"s"(W1h), [pb1]"s"(b1h), [pw2]"s"(W2h),
          [x0]"v"(xi[0]), [x1]"v"(xi[1]), [x2]"v"(xi[2]), [x3]"v"(xi[3]),
          [x4]"v"(xi[4]), [x5]"v"(xi[5]), [x6]"v"(xi[6]), [x7]"v"(xi[7]),
          [x8]"v"(xi[8])
        : "s40","s41","s42","s43","s44","s45","s46","s47","s48","s49",
          "s50","s51","s52","s53","s54","s55","s56","s57","s58","s59",
          "s60","s61","s62",
          "v0","v1","v2","v3",
          "vcc","scc","memory");

    // ---- cross-half reduction (plain HIP: compiler owns LDS/barriers) ----
    if (half) {
#pragma unroll
        for (int t = 0; t < 13; ++t)
            red[t * 128 + el] = make_float2(acc0[t], acc1[t]);
    }
    __syncthreads();
    if (!half) {
#pragma unroll
        for (int t = 0; t < 13; ++t) {
            float2 r = red[t * 128 + el];
            acc0[t] += r.x; acc1[t] += r.y;
        }
    }
    __syncthreads();
    if (half) {
#pragma unroll
        for (int t = 13; t < 25; ++t)
            red[(t - 13) * 128 + el] = make_float2(acc0[t], acc1[t]);
    }
    __syncthreads();
    if (!half) {
#pragma unroll
        for (int t = 13; t < 25; ++t) {
            float2 r = red[(t - 13) * 128 + el];
            acc0[t] += r.x; acc1[t] += r.y;
        }
        // ---- phase 2: output LIF + coalesced float2 stores ----
        const float b20 = b2[0], b21 = b2[1];
        float2* __restrict__ out_spk = (float2*)out;
        float2* __restrict__ out_mem = (float2*)(out + (size_t)T * BATCH * NO);
        float m0 = 0.0f, m1 = 0.0f, s0 = 0.0f, s1 = 0.0f;
#pragma unroll
        for (int t = 0; t < T; ++t) {
            const float c0 = acc0[t] + b20;
            const float c1 = acc1[t] + b21;
            m0 = fmaf(0.95f, m0, c0) - s0;
            m1 = fmaf(0.95f, m1, c1) - s1;
            s0 = (m0 > 1.0f) ? 1.0f : 0.0f;
            s1 = (m1 > 1.0f) ? 1.0f : 0.0f;
            out_spk[(size_t)t * BATCH + e] = make_float2(s0, s1);
            out_mem[(size_t)t * BATCH + e] = make_float2(m0, m1);
        }
    }
}

extern "C" void kernel_launch(void* const* d_in, const int* in_sizes, int n_in,
                              void* d_out, int out_size, void* d_ws, size_t ws_size,
                              hipStream_t stream) {
    const float* x  = (const float*)d_in[0];
    const float* W1 = (const float*)d_in[1];
    const float* b1 = (const float*)d_in[2];
    const float* W2 = (const float*)d_in[3];
    const float* b2 = (const float*)d_in[4];
    float* out = (float*)d_out;

    dim3 block(256);
    dim3 grid(BATCH * 2 / 256);   // 2 threads per element
    snn_fwd<<<grid, block, 0, stream>>>(x, W1, b1, W2, b2, out);
}

// Round 10
// 164.494 us; speedup vs baseline: 1.2408x; 1.0761x over previous
//
#include <hip/hip_runtime.h>

#define BATCH 262144
#define NI 9
#define NH 100
#define NO 2
#define T 25

// R10 = R9 structure (2 threads/elem h-split, asm h-loop with "+v" accs,
// HIP reduction/phase2) with two changes:
// 1. TSTEP is VGPR/inline-only (v4=beta, v5=K hoisted; v6/v7=w0/w1 copied
//    per h). Theory: the ~3.38 vs 3.05 cyc/instr gap is a scalar-operand
//    fetch penalty on VALU ops with SGPR sources (every hot op had one).
// 2. Never-spike skip tightened to the exact 25-step-horizon bound:
//    c <= 0.0625 -> sup_t mem_t = c*(1-b^25)/(1-b) = 14.45c = 0.903 (+fp
//    drift <3e-6) < 1 -> provably spike-free -> skip is exact.
// Per-step math otherwise bit-identical to R7/R9 (passed):
//   mem = fma(beta,mem,c); mem = fmac(-1,spk); pre = fma(K,mem,-K) K=2^60;
//   spk = med3(pre,0,1) [== (mem>1)?1:0 exactly]; acc += w*spk (x2)

#define TSTEP(t) \
  "v_fma_f32 v1, v4, v1, v0\n\t" \
  "v_fmac_f32 v1, -1.0, v2\n\t" \
  "v_fma_f32 v3, v5, v1, -v5\n\t" \
  "v_med3_f32 v2, v3, 0, 1.0\n\t" \
  "v_fmac_f32 %[a" #t "x], v6, v2\n\t" \
  "v_fmac_f32 %[a" #t "y], v7, v2\n\t"

__global__
__attribute__((amdgpu_flat_work_group_size(256, 256), amdgpu_waves_per_eu(6, 8)))
void snn_fwd(
    const float* __restrict__ x,
    const float* __restrict__ W1,
    const float* __restrict__ b1,
    const float* __restrict__ W2,
    const float* __restrict__ b2,
    float* __restrict__ out)
{
    __shared__ float2 red[13 * 128];   // 13 t-slots x 128 elems = 13312 B

    const int tid  = threadIdx.x;
    const int lane = tid & 63;
    const int w    = tid >> 6;
    const int half = __builtin_amdgcn_readfirstlane(w & 1);  // wave-uniform
    const int el   = (w >> 1) * 64 + lane;                   // 0..127
    const int e    = blockIdx.x * 128 + el;

    float xi[NI];
#pragma unroll
    for (int i = 0; i < NI; ++i) xi[i] = x[(size_t)e * NI + i];

    float acc0[T], acc1[T];
#pragma unroll
    for (int t = 0; t < T; ++t) { acc0[t] = 0.0f; acc1[t] = 0.0f; }

    // Uniform (SGPR) h-partition pointers.
    const float* W1h = W1 + half * 50 * NI;
    const float* b1h = b1 + half * 50;
    const float* W2h = W2 + half * 50;   // W2[1,h] at byte offset +0x190

    asm volatile(
        "s_mov_b64 s[40:41], %[pw1]\n\t"
        "s_mov_b64 s[42:43], %[pb1]\n\t"
        "s_mov_b64 s[44:45], %[pw2]\n\t"
        "v_mov_b32 v4, 0x3f733333\n\t"    // beta = 0.95f
        "v_mov_b32 v5, 0x5d800000\n\t"    // K = 2^60
        "s_mov_b32 s62, 50\n\t"           // h counter
        "s_load_dwordx8 s[48:55], s[40:41], 0x0\n\t"
        "s_load_dword s56, s[40:41], 0x20\n\t"
        "s_load_dword s57, s[42:43], 0x0\n\t"
        "s_load_dword s58, s[44:45], 0x0\n\t"
        "s_load_dword s59, s[44:45], 0x190\n\t"
        "1:\n\t"
        "s_waitcnt lgkmcnt(0)\n\t"
        "v_mov_b32 v6, s58\n\t"           // w0 -> VGPR (TSTEP is VGPR-only)
        "v_mov_b32 v7, s59\n\t"           // w1
        "v_mul_f32 v0, s48, %[x0]\n\t"
        "v_fma_f32 v0, s49, %[x1], v0\n\t"
        "v_fma_f32 v0, s50, %[x2], v0\n\t"
        "v_fma_f32 v0, s51, %[x3], v0\n\t"
        "v_fma_f32 v0, s52, %[x4], v0\n\t"
        "v_fma_f32 v0, s53, %[x5], v0\n\t"
        "v_fma_f32 v0, s54, %[x6], v0\n\t"
        "v_fma_f32 v0, s55, %[x7], v0\n\t"
        "v_fma_f32 v0, s56, %[x8], v0\n\t"
        "v_add_f32 v0, s57, v0\n\t"
        // prefetch next h's weights (skip on last iteration)
        "s_cmp_lg_u32 s62, 1\n\t"
        "s_cbranch_scc0 2f\n\t"
        "s_add_u32 s40, s40, 36\n\t"
        "s_addc_u32 s41, s41, 0\n\t"
        "s_add_u32 s42, s42, 4\n\t"
        "s_addc_u32 s43, s43, 0\n\t"
        "s_add_u32 s44, s44, 4\n\t"
        "s_addc_u32 s45, s45, 0\n\t"
        "s_load_dwordx8 s[48:55], s[40:41], 0x0\n\t"
        "s_load_dword s56, s[40:41], 0x20\n\t"
        "s_load_dword s57, s[42:43], 0x0\n\t"
        "s_load_dword s58, s[44:45], 0x0\n\t"
        "s_load_dword s59, s[44:45], 0x190\n\t"
        "2:\n\t"
        // never-spike skip (exact 25-step bound): no lane with c > 0.0625
        "v_cmp_lt_f32 vcc, 0x3d800000, v0\n\t"
        "s_cbranch_vccz 3f\n\t"
        "v_mov_b32 v1, 0\n\t"
        "v_mov_b32 v2, 0\n\t"
        TSTEP(0)  TSTEP(1)  TSTEP(2)  TSTEP(3)  TSTEP(4)
        TSTEP(5)  TSTEP(6)  TSTEP(7)  TSTEP(8)  TSTEP(9)
        TSTEP(10) TSTEP(11) TSTEP(12) TSTEP(13) TSTEP(14)
        TSTEP(15) TSTEP(16) TSTEP(17) TSTEP(18) TSTEP(19)
        TSTEP(20) TSTEP(21) TSTEP(22) TSTEP(23) TSTEP(24)
        "3:\n\t"
        "s_sub_u32 s62, s62, 1\n\t"
        "s_cmp_lg_u32 s62, 0\n\t"
        "s_cbranch_scc1 1b\n\t"
        : [a0x]"+v"(acc0[0]),  [a0y]"+v"(acc1[0]),
          [a1x]"+v"(acc0[1]),  [a1y]"+v"(acc1[1]),
          [a2x]"+v"(acc0[2]),  [a2y]"+v"(acc1[2]),
          [a3x]"+v"(acc0[3]),  [a3y]"+v"(acc1[3]),
          [a4x]"+v"(acc0[4]),  [a4y]"+v"(acc1[4]),
          [a5x]"+v"(acc0[5]),  [a5y]"+v"(acc1[5]),
          [a6x]"+v"(acc0[6]),  [a6y]"+v"(acc1[6]),
          [a7x]"+v"(acc0[7]),  [a7y]"+v"(acc1[7]),
          [a8x]"+v"(acc0[8]),  [a8y]"+v"(acc1[8]),
          [a9x]"+v"(acc0[9]),  [a9y]"+v"(acc1[9]),
          [a10x]"+v"(acc0[10]), [a10y]"+v"(acc1[10]),
          [a11x]"+v"(acc0[11]), [a11y]"+v"(acc1[11]),
          [a12x]"+v"(acc0[12]), [a12y]"+v"(acc1[12]),
          [a13x]"+v"(acc0[13]), [a13y]"+v"(acc1[13]),
          [a14x]"+v"(acc0[14]), [a14y]"+v"(acc1[14]),
          [a15x]"+v"(acc0[15]), [a15y]"+v"(acc1[15]),
          [a16x]"+v"(acc0[16]), [a16y]"+v"(acc1[16]),
          [a17x]"+v"(acc0[17]), [a17y]"+v"(acc1[17]),
          [a18x]"+v"(acc0[18]), [a18y]"+v"(acc1[18]),
          [a19x]"+v"(acc0[19]), [a19y]"+v"(acc1[19]),
          [a20x]"+v"(acc0[20]), [a20y]"+v"(acc1[20]),
          [a21x]"+v"(acc0[21]), [a21y]"+v"(acc1[21]),
          [a22x]"+v"(acc0[22]), [a22y]"+v"(acc1[22]),
          [a23x]"+v"(acc0[23]), [a23y]"+v"(acc1[23]),
          [a24x]"+v"(acc0[24]), [a24y]"+v"(acc1[24])
        : [pw1]"s"(W1h), [pb1]"s"(b1h), [pw2]"s"(W2h),
          [x0]"v"(xi[0]), [x1]"v"(xi[1]), [x2]"v"(xi[2]), [x3]"v"(xi[3]),
          [x4]"v"(xi[4]), [x5]"v"(xi[5]), [x6]"v"(xi[6]), [x7]"v"(xi[7]),
          [x8]"v"(xi[8])
        : "s40","s41","s42","s43","s44","s45","s46","s47","s48","s49",
          "s50","s51","s52","s53","s54","s55","s56","s57","s58","s59",
          "s60","s61","s62",
          "v0","v1","v2","v3","v4","v5","v6","v7",
          "vcc","scc","memory");

    // ---- cross-half reduction (plain HIP: compiler owns LDS/barriers) ----
    if (half) {
#pragma unroll
        for (int t = 0; t < 13; ++t)
            red[t * 128 + el] = make_float2(acc0[t], acc1[t]);
    }
    __syncthreads();
    if (!half) {
#pragma unroll
        for (int t = 0; t < 13; ++t) {
            float2 r = red[t * 128 + el];
            acc0[t] += r.x; acc1[t] += r.y;
        }
    }
    __syncthreads();
    if (half) {
#pragma unroll
        for (int t = 13; t < 25; ++t)
            red[(t - 13) * 128 + el] = make_float2(acc0[t], acc1[t]);
    }
    __syncthreads();
    if (!half) {
#pragma unroll
        for (int t = 13; t < 25; ++t) {
            float2 r = red[(t - 13) * 128 + el];
            acc0[t] += r.x; acc1[t] += r.y;
        }
        // ---- phase 2: output LIF + coalesced float2 stores ----
        const float b20 = b2[0], b21 = b2[1];
        float2* __restrict__ out_spk = (float2*)out;
        float2* __restrict__ out_mem = (float2*)(out + (size_t)T * BATCH * NO);
        float m0 = 0.0f, m1 = 0.0f, s0 = 0.0f, s1 = 0.0f;
#pragma unroll
        for (int t = 0; t < T; ++t) {
            const float c0 = acc0[t] + b20;
            const float c1 = acc1[t] + b21;
            m0 = fmaf(0.95f, m0, c0) - s0;
            m1 = fmaf(0.95f, m1, c1) - s1;
            s0 = (m0 > 1.0f) ? 1.0f : 0.0f;
            s1 = (m1 > 1.0f) ? 1.0f : 0.0f;
            out_spk[(size_t)t * BATCH + e] = make_float2(s0, s1);
            out_mem[(size_t)t * BATCH + e] = make_float2(m0, m1);
        }
    }
}

extern "C" void kernel_launch(void* const* d_in, const int* in_sizes, int n_in,
                              void* d_out, int out_size, void* d_ws, size_t ws_size,
                              hipStream_t stream) {
    const float* x  = (const float*)d_in[0];
    const float* W1 = (const float*)d_in[1];
    const float* b1 = (const float*)d_in[2];
    const float* W2 = (const float*)d_in[3];
    const float* b2 = (const float*)d_in[4];
    float* out = (float*)d_out;

    dim3 block(256);
    dim3 grid(BATCH * 2 / 256);   // 2 threads per element
    snn_fwd<<<grid, block, 0, stream>>>(x, W1, b1, W2, b2, out);
}